// Round 11
// baseline (1466.470 us; speedup 1.0000x reference)
//
#include <hip/hip_runtime.h>
#include <hip/hip_bf16.h>

#define DD 128
#define NEG 0.2f

typedef short bf16x8 __attribute__((ext_vector_type(8)));
typedef float f32x4 __attribute__((ext_vector_type(4)));

__device__ inline ushort f2bf(float x) {
  unsigned u = __float_as_uint(x);
  return (ushort)((u + 0x7FFF + ((u >> 16) & 1)) >> 16);
}
__device__ inline float bf2f(ushort u) { return __uint_as_float((unsigned)u << 16); }

// ---------------- atom encoder: writes h as hi/lo bf16 split ---------------------
__global__ void k_atom_enc(const int* __restrict__ x, const float* __restrict__ tab,
                           ushort* __restrict__ h_hi, ushort* __restrict__ h_lo, int N) {
  int idx = blockIdx.x * blockDim.x + threadIdx.x;
  if (idx >= N * DD) return;
  int n = idx >> 7, d = idx & 127;
  const int* xr = x + n * 9;
  float s = 0.f;
#pragma unroll
  for (int f = 0; f < 9; f++) s += tab[(f * 16 + xr[f]) * DD + d];
  ushort hi = f2bf(s);
  h_hi[idx] = hi;
  h_lo[idx] = f2bf(s - bf2f(hi));
}

// ---------------- init deg(=1 self loop), cnt, sums ----------------
__global__ void k_init(int* __restrict__ deg, float* __restrict__ cnt,
                       float* __restrict__ sums, int N) {
  int i = blockIdx.x * blockDim.x + threadIdx.x;
  if (i >= N) return;
  deg[i] = 1;
  cnt[i] = 0.f;
  sums[i * 4 + 0] = 0.f; sums[i * 4 + 1] = 0.f;
  sums[i * 4 + 2] = 0.f; sums[i * 4 + 3] = 0.f;
}

// ---------------- per real edge: bond emb, per-dst sums/cnt/deg ----------------
__global__ void k_edge_count(const int* __restrict__ ei, const int* __restrict__ eattr,
                             const float* __restrict__ btab, float* __restrict__ e_emb,
                             float* __restrict__ sums, float* __restrict__ cnt,
                             int* __restrict__ deg, int E) {
  int e = blockIdx.x * blockDim.x + threadIdx.x;
  if (e >= E) return;
  int d = ei[E + e];
  int a = eattr[e];
  float f0 = btab[a * 4 + 0], f1 = btab[a * 4 + 1];
  float f2 = btab[a * 4 + 2], f3 = btab[a * 4 + 3];
  e_emb[e * 4 + 0] = f0; e_emb[e * 4 + 1] = f1;
  e_emb[e * 4 + 2] = f2; e_emb[e * 4 + 3] = f3;
  atomicAdd(&sums[d * 4 + 0], f0);
  atomicAdd(&sums[d * 4 + 1], f1);
  atomicAdd(&sums[d * 4 + 2], f2);
  atomicAdd(&sums[d * 4 + 3], f3);
  atomicAdd(&cnt[d], 1.0f);
  atomicAdd(&deg[d], 1);
}

// ---------------- loop_attr (in-place on sums) ----------------
__global__ void k_loopattr(float* __restrict__ sums, const float* __restrict__ cnt, int N) {
  int i = blockIdx.x * blockDim.x + threadIdx.x;
  if (i >= N * 4) return;
  sums[i] = sums[i] / fmaxf(cnt[i >> 2], 1.0f);
}

// ---------------- scan: chunk = 2048 (256 thr x 8 items) ----------------
__global__ void k_scan_block(const int* __restrict__ deg, int* __restrict__ bsums, int N) {
  __shared__ int sh[256];
  int t = threadIdx.x;
  int base = blockIdx.x * 2048 + t * 8;
  int tot = 0;
#pragma unroll
  for (int i = 0; i < 8; i++) tot += (base + i < N) ? deg[base + i] : 0;
  sh[t] = tot;
  __syncthreads();
  for (int off = 128; off > 0; off >>= 1) {
    if (t < off) sh[t] += sh[t + off];
    __syncthreads();
  }
  if (t == 0) bsums[blockIdx.x] = sh[0];
}

__global__ void k_scan_top(int* __restrict__ bsums, int* __restrict__ rowptr,
                           int nblk, int N) {
  if (threadIdx.x == 0 && blockIdx.x == 0) {
    int run = 0;
    for (int b = 0; b < nblk; b++) { int v = bsums[b]; bsums[b] = run; run += v; }
    rowptr[N] = run;
  }
}

__global__ void k_scan_down(const int* __restrict__ deg, const int* __restrict__ bsums,
                            int* __restrict__ rowptr, int* __restrict__ cursor, int N) {
  __shared__ int sh[256];
  int t = threadIdx.x;
  int base = blockIdx.x * 2048 + t * 8;
  int v[8]; int tot = 0;
#pragma unroll
  for (int i = 0; i < 8; i++) { v[i] = (base + i < N) ? deg[base + i] : 0; tot += v[i]; }
  sh[t] = tot;
  __syncthreads();
  for (int off = 1; off < 256; off <<= 1) {
    int xv = (t >= off) ? sh[t - off] : 0;
    __syncthreads();
    sh[t] += xv;
    __syncthreads();
  }
  int run = bsums[blockIdx.x] + sh[t] - tot;
#pragma unroll
  for (int i = 0; i < 8; i++) {
    if (base + i < N) { rowptr[base + i] = run; cursor[base + i] = run; run += v[i]; }
  }
}

// ---------------- scatter edge ids into CSR -------------------------------------
__global__ void k_scatter(const int* __restrict__ ei, int* __restrict__ cursor,
                          int* __restrict__ eid, int E, int N) {
  int t = blockIdx.x * blockDim.x + threadIdx.x;
  if (t >= E + N) return;
  int d = (t < E) ? ei[E + t] : (t - E);
  int pos = atomicAdd(&cursor[d], 1);
  eid[pos] = t;
}

// ---------------- W prepack: bf16 hi/lo split into MFMA fragment order -----------
__global__ void k_wpack(const float* __restrict__ Wl, const float* __restrict__ Wr,
                        ushort* __restrict__ Bhi, ushort* __restrict__ Blo, int L) {
  int tid = blockIdx.x * blockDim.x + threadIdx.x;
  int total = L * 2 * 4 * 8 * 64;
  if (tid >= total) return;
  int lane = tid & 63;
  int nt = (tid >> 6) & 7;
  int kb = (tid >> 9) & 3;
  int mat = (tid >> 11) & 1;
  int layer = tid >> 12;
  const float* W = (mat ? Wr : Wl) + (size_t)layer * DD * DD;
  int kbase = kb * 32 + (lane >> 4) * 8;
  int n = nt * 16 + (lane & 15);
  size_t out = (size_t)(layer * 2 + mat) * 16384 +
               ((size_t)(kb * 8 + nt) * 64 + lane) * 8;
#pragma unroll
  for (int j = 0; j < 8; j++) {
    float xv = W[(size_t)(kbase + j) * DD + n];
    ushort h_ = f2bf(xv);
    float fh = __uint_as_float((unsigned)h_ << 16);
    ushort l_ = f2bf(xv - fh);
    Bhi[out + j] = h_;
    Blo[out + j] = l_;
  }
}

// ---------------- fused xl/xr GEMM via bf16x3 MFMA, NO LDS -----------------------
// h stored pre-split as hi/lo bf16 -> A-frags load directly from global (bf16x8);
// intra-block 4x reuse served by L1. No conversion VALU, no barrier.
// h_hi/h_lo over-allocated by 64 rows so tail-block reads are in-bounds.
__global__ __launch_bounds__(256) void k_gemm2_mfma(
    const ushort* __restrict__ h_hi, const ushort* __restrict__ h_lo,
    const ushort* __restrict__ bhiL, const ushort* __restrict__ bloL,
    const ushort* __restrict__ bhiR, const ushort* __restrict__ bloR,
    const float* __restrict__ bl, const float* __restrict__ br,
    ushort* __restrict__ xlb, ushort* __restrict__ xrb, int N) {
  int t = threadIdx.x;
  int lane = t & 63, w = t >> 6;
  int A0 = blockIdx.x * 64;
  int arow = lane & 15;
  int kg = lane >> 4;                        // k-group (8 bf16 each)

  f32x4 accL[4][2], accR[4][2];
#pragma unroll
  for (int mt = 0; mt < 4; mt++)
#pragma unroll
    for (int nti = 0; nti < 2; nti++) {
      accL[mt][nti] = (f32x4){0.f, 0.f, 0.f, 0.f};
      accR[mt][nti] = (f32x4){0.f, 0.f, 0.f, 0.f};
    }

#pragma unroll
  for (int kb = 0; kb < 4; kb++) {
    bf16x8 ahi[4], alo[4];
#pragma unroll
    for (int mt = 0; mt < 4; mt++) {
      size_t aoff = (size_t)(A0 + mt * 16 + arow) * DD + kb * 32 + kg * 8;
      ahi[mt] = *(const bf16x8*)&h_hi[aoff];
      alo[mt] = *(const bf16x8*)&h_lo[aoff];
    }
#pragma unroll
    for (int nti = 0; nti < 2; nti++) {
      int nt = w * 2 + nti;
      size_t fo = ((size_t)(kb * 8 + nt) * 64 + lane) * 8;
      bf16x8 bhl = *(const bf16x8*)(bhiL + fo);
      bf16x8 bll = *(const bf16x8*)(bloL + fo);
      bf16x8 bhr = *(const bf16x8*)(bhiR + fo);
      bf16x8 blr = *(const bf16x8*)(bloR + fo);
#pragma unroll
      for (int mt = 0; mt < 4; mt++) {
        accL[mt][nti] = __builtin_amdgcn_mfma_f32_16x16x32_bf16(ahi[mt], bhl, accL[mt][nti], 0, 0, 0);
        accR[mt][nti] = __builtin_amdgcn_mfma_f32_16x16x32_bf16(ahi[mt], bhr, accR[mt][nti], 0, 0, 0);
        accL[mt][nti] = __builtin_amdgcn_mfma_f32_16x16x32_bf16(ahi[mt], bll, accL[mt][nti], 0, 0, 0);
        accR[mt][nti] = __builtin_amdgcn_mfma_f32_16x16x32_bf16(ahi[mt], blr, accR[mt][nti], 0, 0, 0);
        accL[mt][nti] = __builtin_amdgcn_mfma_f32_16x16x32_bf16(alo[mt], bhl, accL[mt][nti], 0, 0, 0);
        accR[mt][nti] = __builtin_amdgcn_mfma_f32_16x16x32_bf16(alo[mt], bhr, accR[mt][nti], 0, 0, 0);
      }
    }
  }

  // epilogue: D row=(lane>>4)*4+r, col=lane&15; bf16 stores
  int col = lane & 15;
  int rgrp = (lane >> 4) * 4;
#pragma unroll
  for (int nti = 0; nti < 2; nti++) {
    int n = (w * 2 + nti) * 16 + col;
    float bLv = bl[n], bRv = br[n];
#pragma unroll
    for (int mt = 0; mt < 4; mt++) {
#pragma unroll
      for (int r = 0; r < 4; r++) {
        int atom = A0 + mt * 16 + rgrp + r;
        if (atom < N) {
          xlb[(size_t)atom * DD + n] = f2bf(accL[mt][nti][r] + bLv);
          xrb[(size_t)atom * DD + n] = f2bf(accR[mt][nti][r] + bRv);
        }
      }
    }
  }
}

// ---------------- attention: 1 wave/node, 4 groups x 16 lanes --------------------
// Group g handles edges r0+g, r0+g+4, ... ; lane q owns channels [q*8, q*8+8)
// (bf16x8 = one 16B load per edge per lane). Logits are tiny (inputs scaled 0.05)
// so softmax needs NO max subtraction: z/acc are pure associative sums -> no
// serial chain, cross-group combine is one butterfly at the end.
// Per edge: 1 eid + 1 ei + 1 e_emb + 1 xl load instruction per GROUP (4 edges in
// flight per wave), 2 shfl for the per-head dot.
__global__ __launch_bounds__(256) void k_attn(
    const ushort* __restrict__ xlb, const ushort* __restrict__ xrb,
    const float* __restrict__ e_emb, const float* __restrict__ la,
    const int* __restrict__ ei, const int* __restrict__ rowptr,
    const int* __restrict__ eid,
    const float* __restrict__ Wep, const float* __restrict__ attp,
    const float* __restrict__ cbp,
    const float* __restrict__ Woutp, const int* __restrict__ bid,
    float* __restrict__ outp,
    ushort* __restrict__ h_hi, ushort* __restrict__ h_lo,
    int N, int E, int flags) {
  __shared__ float sv[4];
  __shared__ int   sb[4];
  int wid = threadIdx.x >> 6;
  int lane = threadIdx.x & 63;
  int g = lane >> 4, q = lane & 15;
  int n = blockIdx.x * 4 + wid;
  bool act = n < N;
  int nn = act ? n : (N - 1);                 // clamp for safe loads
  int c0 = q * 8;
  int head = q >> 2;

  float we[4][8];
#pragma unroll
  for (int j = 0; j < 4; j++)
#pragma unroll
    for (int c = 0; c < 8; c++) we[j][c] = Wep[j * DD + c0 + c];
  float av[8];
#pragma unroll
  for (int c = 0; c < 8; c++) av[c] = attp[head * 32 + ((c0 + c) & 31)];
  float xr[8];
  {
    bf16x8 u = *(const bf16x8*)&xrb[(size_t)nn * DD + c0];
#pragma unroll
    for (int c = 0; c < 8; c++) xr[c] = bf2f((ushort)u[c]);
  }
  float4 la4 = *(const float4*)&la[(size_t)nn * 4];

  float z = 0.f;
  float acc[8];
#pragma unroll
  for (int c = 0; c < 8; c++) acc[c] = 0.f;

  int r0 = rowptr[nn], r1 = rowptr[nn + 1];
  for (int p0 = r0; p0 < r1; p0 += 4) {
    int p = p0 + g;
    float msk = (p < r1) ? 1.f : 0.f;
    p = (p < r1) ? p : (r1 - 1);
    int e = eid[p];
    bool re = e < E;
    int eidx = re ? e : 0;
    float4 f = *(const float4*)&e_emb[(size_t)eidx * 4];
    if (!re) f = la4;
    int s = re ? ei[eidx] : nn;
    bf16x8 u = *(const bf16x8*)&xlb[(size_t)s * DD + c0];
    float xv[8];
#pragma unroll
    for (int c = 0; c < 8; c++) xv[c] = bf2f((ushort)u[c]);
    float pv = 0.f;
#pragma unroll
    for (int c = 0; c < 8; c++) {
      float ee = f.x * we[0][c] + f.y * we[1][c] + f.z * we[2][c] + f.w * we[3][c];
      float gg = xv[c] + xr[c] + ee;
      gg = gg > 0.f ? gg : NEG * gg;
      pv += gg * av[c];
    }
    // per-head logit: sum the 4 lanes of this head (q bits 0,1)
    pv += __shfl_xor(pv, 1);
    pv += __shfl_xor(pv, 2);
    float wj = __expf(pv) * msk;                // no max-subtraction: logits tiny
    z += wj;
#pragma unroll
    for (int c = 0; c < 8; c++) acc[c] += wj * xv[c];
  }
  // combine the 4 groups' partial sums
  z += __shfl_xor(z, 16);
  z += __shfl_xor(z, 32);
#pragma unroll
  for (int c = 0; c < 8; c++) {
    acc[c] += __shfl_xor(acc[c], 16);
    acc[c] += __shfl_xor(acc[c], 32);
  }
  float inv = 1.f / (z + 1e-16f);
  float o[8];
#pragma unroll
  for (int c = 0; c < 8; c++) {
    o[c] = acc[c] * inv + cbp[c0 + c];
    if (flags & 1) o[c] = fmaxf(o[c], 0.f);
  }

  if (flags & 2) {
    // fused head: full-row dot = reduce over the 16 lanes of a group
    float v = 0.f;
#pragma unroll
    for (int c = 0; c < 8; c++) v += o[c] * Woutp[c0 + c];
    v += __shfl_xor(v, 1);
    v += __shfl_xor(v, 2);
    v += __shfl_xor(v, 4);
    v += __shfl_xor(v, 8);
    if (lane == 0) {
      sv[wid] = act ? v : 0.f;
      sb[wid] = act ? bid[n] : -1;
    }
    __syncthreads();
    if (threadIdx.x == 0) {
      int i = 0;
      while (i < 4) {
        int b = sb[i];
        if (b < 0) { i++; continue; }
        float s2 = sv[i];
        int j = i + 1;
        while (j < 4 && sb[j] == b) { s2 += sv[j]; j++; }
        atomicAdd(&outp[b], s2);
        i = j;
      }
    }
  } else if (act && g == 0) {
    bf16x8 vh, vl;
#pragma unroll
    for (int c = 0; c < 8; c++) {
      ushort hi = f2bf(o[c]);
      vh[c] = (short)hi;
      vl[c] = (short)f2bf(o[c] - bf2f(hi));
    }
    *(bf16x8*)&h_hi[(size_t)n * DD + c0] = vh;
    *(bf16x8*)&h_lo[(size_t)n * DD + c0] = vl;
  }
}

// ---------------- out init: out[g] = bout ----------------------------------------
__global__ void k_head_init(float* __restrict__ out, const float* __restrict__ bout, int G) {
  int i = blockIdx.x * blockDim.x + threadIdx.x;
  if (i < G) out[i] = bout[0];
}

extern "C" void kernel_launch(void* const* d_in, const int* in_sizes, int n_in,
                              void* d_out, int out_size, void* d_ws, size_t ws_size,
                              hipStream_t stream) {
  const float* atom_tables = (const float*)d_in[0];
  const float* bond_table  = (const float*)d_in[1];
  const float* Wl   = (const float*)d_in[2];
  const float* bl   = (const float*)d_in[3];
  const float* Wr   = (const float*)d_in[4];
  const float* br   = (const float*)d_in[5];
  const float* We   = (const float*)d_in[6];
  const float* att  = (const float*)d_in[7];
  const float* cb   = (const float*)d_in[8];
  const float* Wout = (const float*)d_in[9];
  const float* bout = (const float*)d_in[10];
  const int* x      = (const int*)d_in[11];
  const int* ei     = (const int*)d_in[12];
  const int* eattr  = (const int*)d_in[13];
  const int* bid    = (const int*)d_in[14];

  int N = in_sizes[11] / 9;
  int E = in_sizes[13];
  int G = out_size;          // NTASK == 1
  int L = in_sizes[3] / DD;  // 4 layers

  char* p = (char*)d_ws;
  auto alloc = [&](size_t bytes) {
    char* r = p;
    p += (bytes + 255) & ~(size_t)255;
    return r;
  };
  // h hi/lo bf16 (over-alloc +64 rows for gemm tail reads), xl/xr bf16
  ushort* h_hi   = (ushort*)alloc((size_t)(N + 64) * DD * 2);  // 51.2 MB
  ushort* h_lo   = (ushort*)alloc((size_t)(N + 64) * DD * 2);  // 51.2 MB
  ushort* xlb    = (ushort*)alloc((size_t)N * DD * 2);         // 51.2 MB
  ushort* xrb    = (ushort*)alloc((size_t)N * DD * 2);         // 51.2 MB
  float*  e_emb  = (float*)alloc((size_t)E * 4 * 4);           // 6.4 MB
  float*  sums   = (float*)alloc((size_t)N * 4 * 4);           // loop_attr
  int*    rowptr = (int*)alloc((size_t)(N + 1) * 4);
  int*    eid    = (int*)alloc((size_t)(E + N) * 4);
  float*  cnt    = (float*)alloc((size_t)N * 4);
  int*    deg    = (int*)alloc((size_t)N * 4);
  int*    cursor = (int*)alloc((size_t)N * 4);
  int nblk = (N + 2047) / 2048;
  int*    bsums  = (int*)alloc((size_t)nblk * 4);
  ushort* Bhi    = (ushort*)alloc((size_t)L * 2 * 16384 * 2);
  ushort* Blo    = (ushort*)alloc((size_t)L * 2 * 16384 * 2);
  float*  out    = (float*)d_out;

  // Diagnostic guard: ws too small -> clean absmax failure, not a memory fault.
  if ((size_t)(p - (char*)d_ws) > ws_size) return;

  hipLaunchKernelGGL(k_atom_enc, dim3((N * DD + 255) / 256), dim3(256), 0, stream,
                     x, atom_tables, h_hi, h_lo, N);
  hipLaunchKernelGGL(k_init, dim3((N + 255) / 256), dim3(256), 0, stream,
                     deg, cnt, sums, N);
  hipLaunchKernelGGL(k_edge_count, dim3((E + 255) / 256), dim3(256), 0, stream,
                     ei, eattr, bond_table, e_emb, sums, cnt, deg, E);
  hipLaunchKernelGGL(k_scan_block, dim3(nblk), dim3(256), 0, stream, deg, bsums, N);
  hipLaunchKernelGGL(k_scan_top, dim3(1), dim3(64), 0, stream, bsums, rowptr, nblk, N);
  hipLaunchKernelGGL(k_scan_down, dim3(nblk), dim3(256), 0, stream,
                     deg, bsums, rowptr, cursor, N);
  hipLaunchKernelGGL(k_scatter, dim3((E + N + 255) / 256), dim3(256), 0, stream,
                     ei, cursor, eid, E, N);
  hipLaunchKernelGGL(k_loopattr, dim3((N * 4 + 255) / 256), dim3(256), 0, stream,
                     sums, cnt, N);
  {
    int total = L * 2 * 4 * 8 * 64;
    hipLaunchKernelGGL(k_wpack, dim3((total + 255) / 256), dim3(256), 0, stream,
                       Wl, Wr, Bhi, Blo, L);
  }
  hipLaunchKernelGGL(k_head_init, dim3((G + 255) / 256), dim3(256), 0, stream,
                     out, bout, G);

  for (int l = 0; l < L; l++) {
    const ushort* bhiL = Bhi + (size_t)(l * 2 + 0) * 16384;
    const ushort* bhiR = Bhi + (size_t)(l * 2 + 1) * 16384;
    const ushort* bloL = Blo + (size_t)(l * 2 + 0) * 16384;
    const ushort* bloR = Blo + (size_t)(l * 2 + 1) * 16384;
    hipLaunchKernelGGL(k_gemm2_mfma, dim3((N + 63) / 64), dim3(256), 0, stream,
                       h_hi, h_lo, bhiL, bloL, bhiR, bloR,
                       bl + (size_t)l * DD, br + (size_t)l * DD, xlb, xrb, N);
    int flags = (l < L - 1) ? 1 : 2;   // relu inner; head-fusion last
    hipLaunchKernelGGL(k_attn, dim3((N + 3) / 4), dim3(256), 0, stream,
                       xlb, xrb, e_emb, sums, ei, rowptr, eid,
                       We + (size_t)l * 4 * DD, att + (size_t)l * 4 * 32,
                       cb + (size_t)l * DD, Wout, bid, out, h_hi, h_lo, N, E, flags);
  }
}

// Round 12
// 1217.790 us; speedup vs baseline: 1.2042x; 1.2042x over previous
//
#include <hip/hip_runtime.h>
#include <hip/hip_bf16.h>

#define DD 128
#define NEG 0.2f

typedef short bf16x8 __attribute__((ext_vector_type(8)));
typedef float f32x4 __attribute__((ext_vector_type(4)));

__device__ inline ushort f2bf(float x) {
  unsigned u = __float_as_uint(x);
  return (ushort)((u + 0x7FFF + ((u >> 16) & 1)) >> 16);
}
__device__ inline float bf2f(ushort u) { return __uint_as_float((unsigned)u << 16); }

// ---------------- atom encoder: writes h as hi/lo bf16 split ---------------------
__global__ void k_atom_enc(const int* __restrict__ x, const float* __restrict__ tab,
                           ushort* __restrict__ h_hi, ushort* __restrict__ h_lo, int N) {
  int idx = blockIdx.x * blockDim.x + threadIdx.x;
  if (idx >= N * DD) return;
  int n = idx >> 7, d = idx & 127;
  const int* xr = x + n * 9;
  float s = 0.f;
#pragma unroll
  for (int f = 0; f < 9; f++) s += tab[(f * 16 + xr[f]) * DD + d];
  ushort hi = f2bf(s);
  h_hi[idx] = hi;
  h_lo[idx] = f2bf(s - bf2f(hi));
}

// ---------------- init deg(=1 self loop), cnt, sums ----------------
__global__ void k_init(int* __restrict__ deg, float* __restrict__ cnt,
                       float* __restrict__ sums, int N) {
  int i = blockIdx.x * blockDim.x + threadIdx.x;
  if (i >= N) return;
  deg[i] = 1;
  cnt[i] = 0.f;
  sums[i * 4 + 0] = 0.f; sums[i * 4 + 1] = 0.f;
  sums[i * 4 + 2] = 0.f; sums[i * 4 + 3] = 0.f;
}

// ---------------- per real edge: bond emb, per-dst sums/cnt/deg ----------------
__global__ void k_edge_count(const int* __restrict__ ei, const int* __restrict__ eattr,
                             const float* __restrict__ btab, float* __restrict__ e_emb,
                             float* __restrict__ sums, float* __restrict__ cnt,
                             int* __restrict__ deg, int E) {
  int e = blockIdx.x * blockDim.x + threadIdx.x;
  if (e >= E) return;
  int d = ei[E + e];
  int a = eattr[e];
  float f0 = btab[a * 4 + 0], f1 = btab[a * 4 + 1];
  float f2 = btab[a * 4 + 2], f3 = btab[a * 4 + 3];
  e_emb[e * 4 + 0] = f0; e_emb[e * 4 + 1] = f1;
  e_emb[e * 4 + 2] = f2; e_emb[e * 4 + 3] = f3;
  atomicAdd(&sums[d * 4 + 0], f0);
  atomicAdd(&sums[d * 4 + 1], f1);
  atomicAdd(&sums[d * 4 + 2], f2);
  atomicAdd(&sums[d * 4 + 3], f3);
  atomicAdd(&cnt[d], 1.0f);
  atomicAdd(&deg[d], 1);
}

// ---------------- loop_attr (in-place on sums) ----------------
__global__ void k_loopattr(float* __restrict__ sums, const float* __restrict__ cnt, int N) {
  int i = blockIdx.x * blockDim.x + threadIdx.x;
  if (i >= N * 4) return;
  sums[i] = sums[i] / fmaxf(cnt[i >> 2], 1.0f);
}

// ---------------- scan: chunk = 2048 (256 thr x 8 items) ----------------
__global__ void k_scan_block(const int* __restrict__ deg, int* __restrict__ bsums, int N) {
  __shared__ int sh[256];
  int t = threadIdx.x;
  int base = blockIdx.x * 2048 + t * 8;
  int tot = 0;
#pragma unroll
  for (int i = 0; i < 8; i++) tot += (base + i < N) ? deg[base + i] : 0;
  sh[t] = tot;
  __syncthreads();
  for (int off = 128; off > 0; off >>= 1) {
    if (t < off) sh[t] += sh[t + off];
    __syncthreads();
  }
  if (t == 0) bsums[blockIdx.x] = sh[0];
}

__global__ void k_scan_top(int* __restrict__ bsums, int* __restrict__ rowptr,
                           int nblk, int N) {
  if (threadIdx.x == 0 && blockIdx.x == 0) {
    int run = 0;
    for (int b = 0; b < nblk; b++) { int v = bsums[b]; bsums[b] = run; run += v; }
    rowptr[N] = run;
  }
}

__global__ void k_scan_down(const int* __restrict__ deg, const int* __restrict__ bsums,
                            int* __restrict__ rowptr, int* __restrict__ cursor, int N) {
  __shared__ int sh[256];
  int t = threadIdx.x;
  int base = blockIdx.x * 2048 + t * 8;
  int v[8]; int tot = 0;
#pragma unroll
  for (int i = 0; i < 8; i++) { v[i] = (base + i < N) ? deg[base + i] : 0; tot += v[i]; }
  sh[t] = tot;
  __syncthreads();
  for (int off = 1; off < 256; off <<= 1) {
    int xv = (t >= off) ? sh[t - off] : 0;
    __syncthreads();
    sh[t] += xv;
    __syncthreads();
  }
  int run = bsums[blockIdx.x] + sh[t] - tot;
#pragma unroll
  for (int i = 0; i < 8; i++) {
    if (base + i < N) { rowptr[base + i] = run; cursor[base + i] = run; run += v[i]; }
  }
}

// ---------------- scatter edge ids into CSR -------------------------------------
__global__ void k_scatter(const int* __restrict__ ei, int* __restrict__ cursor,
                          int* __restrict__ eid, int E, int N) {
  int t = blockIdx.x * blockDim.x + threadIdx.x;
  if (t >= E + N) return;
  int d = (t < E) ? ei[E + t] : (t - E);
  int pos = atomicAdd(&cursor[d], 1);
  eid[pos] = t;
}

// ---------------- slot packing: kill one pointer-chase level ---------------------
// Per CSR position p, materialize src node and edge features once per launch.
// Attn loop then loads slot_src[p] + slot_emb[p] directly (chain depth 2, no
// e<E select, no la fallback).
__global__ void k_slotfill(const int* __restrict__ eid, const int* __restrict__ ei,
                           const float* __restrict__ e_emb, const float* __restrict__ la,
                           int* __restrict__ slot_src, float* __restrict__ slot_emb,
                           int E, int total) {
  int p = blockIdx.x * blockDim.x + threadIdx.x;
  if (p >= total) return;
  int t = eid[p];
  bool re = t < E;
  int src = re ? ei[t] : (t - E);
  const float* fp = re ? &e_emb[(size_t)t * 4] : &la[(size_t)(t - E) * 4];
  slot_src[p] = src;
  *(float4*)&slot_emb[(size_t)p * 4] = *(const float4*)fp;
}

// ---------------- W prepack: bf16 hi/lo split into MFMA fragment order -----------
__global__ void k_wpack(const float* __restrict__ Wl, const float* __restrict__ Wr,
                        ushort* __restrict__ Bhi, ushort* __restrict__ Blo, int L) {
  int tid = blockIdx.x * blockDim.x + threadIdx.x;
  int total = L * 2 * 4 * 8 * 64;
  if (tid >= total) return;
  int lane = tid & 63;
  int nt = (tid >> 6) & 7;
  int kb = (tid >> 9) & 3;
  int mat = (tid >> 11) & 1;
  int layer = tid >> 12;
  const float* W = (mat ? Wr : Wl) + (size_t)layer * DD * DD;
  int kbase = kb * 32 + (lane >> 4) * 8;
  int n = nt * 16 + (lane & 15);
  size_t out = (size_t)(layer * 2 + mat) * 16384 +
               ((size_t)(kb * 8 + nt) * 64 + lane) * 8;
#pragma unroll
  for (int j = 0; j < 8; j++) {
    float xv = W[(size_t)(kbase + j) * DD + n];
    ushort h_ = f2bf(xv);
    float fh = __uint_as_float((unsigned)h_ << 16);
    ushort l_ = f2bf(xv - fh);
    Bhi[out + j] = h_;
    Blo[out + j] = l_;
  }
}

// ---------------- fused xl/xr GEMM via bf16x3 MFMA, NO LDS -----------------------
// h stored pre-split as hi/lo bf16 -> A-frags load directly from global (bf16x8);
// intra-block 4x reuse served by L1. h_hi/h_lo over-allocated +64 rows for tail.
__global__ __launch_bounds__(256) void k_gemm2_mfma(
    const ushort* __restrict__ h_hi, const ushort* __restrict__ h_lo,
    const ushort* __restrict__ bhiL, const ushort* __restrict__ bloL,
    const ushort* __restrict__ bhiR, const ushort* __restrict__ bloR,
    const float* __restrict__ bl, const float* __restrict__ br,
    ushort* __restrict__ xlb, ushort* __restrict__ xrb, int N) {
  int t = threadIdx.x;
  int lane = t & 63, w = t >> 6;
  int A0 = blockIdx.x * 64;
  int arow = lane & 15;
  int kg = lane >> 4;

  f32x4 accL[4][2], accR[4][2];
#pragma unroll
  for (int mt = 0; mt < 4; mt++)
#pragma unroll
    for (int nti = 0; nti < 2; nti++) {
      accL[mt][nti] = (f32x4){0.f, 0.f, 0.f, 0.f};
      accR[mt][nti] = (f32x4){0.f, 0.f, 0.f, 0.f};
    }

#pragma unroll
  for (int kb = 0; kb < 4; kb++) {
    bf16x8 ahi[4], alo[4];
#pragma unroll
    for (int mt = 0; mt < 4; mt++) {
      size_t aoff = (size_t)(A0 + mt * 16 + arow) * DD + kb * 32 + kg * 8;
      ahi[mt] = *(const bf16x8*)&h_hi[aoff];
      alo[mt] = *(const bf16x8*)&h_lo[aoff];
    }
#pragma unroll
    for (int nti = 0; nti < 2; nti++) {
      int nt = w * 2 + nti;
      size_t fo = ((size_t)(kb * 8 + nt) * 64 + lane) * 8;
      bf16x8 bhl = *(const bf16x8*)(bhiL + fo);
      bf16x8 bll = *(const bf16x8*)(bloL + fo);
      bf16x8 bhr = *(const bf16x8*)(bhiR + fo);
      bf16x8 blr = *(const bf16x8*)(bloR + fo);
#pragma unroll
      for (int mt = 0; mt < 4; mt++) {
        accL[mt][nti] = __builtin_amdgcn_mfma_f32_16x16x32_bf16(ahi[mt], bhl, accL[mt][nti], 0, 0, 0);
        accR[mt][nti] = __builtin_amdgcn_mfma_f32_16x16x32_bf16(ahi[mt], bhr, accR[mt][nti], 0, 0, 0);
        accL[mt][nti] = __builtin_amdgcn_mfma_f32_16x16x32_bf16(ahi[mt], bll, accL[mt][nti], 0, 0, 0);
        accR[mt][nti] = __builtin_amdgcn_mfma_f32_16x16x32_bf16(ahi[mt], blr, accR[mt][nti], 0, 0, 0);
        accL[mt][nti] = __builtin_amdgcn_mfma_f32_16x16x32_bf16(alo[mt], bhl, accL[mt][nti], 0, 0, 0);
        accR[mt][nti] = __builtin_amdgcn_mfma_f32_16x16x32_bf16(alo[mt], bhr, accR[mt][nti], 0, 0, 0);
      }
    }
  }

  int col = lane & 15;
  int rgrp = (lane >> 4) * 4;
#pragma unroll
  for (int nti = 0; nti < 2; nti++) {
    int n = (w * 2 + nti) * 16 + col;
    float bLv = bl[n], bRv = br[n];
#pragma unroll
    for (int mt = 0; mt < 4; mt++) {
#pragma unroll
      for (int r = 0; r < 4; r++) {
        int atom = A0 + mt * 16 + rgrp + r;
        if (atom < N) {
          xlb[(size_t)atom * DD + n] = f2bf(accL[mt][nti][r] + bLv);
          xrb[(size_t)atom * DD + n] = f2bf(accR[mt][nti][r] + bRv);
        }
      }
    }
  }
}

// ---------------- attention: R5 structure (measured-best) + bf16 + slots ---------
// 1 wave/node, 2 channels/lane, 16-lane butterfly per head. Simple per-edge loop,
// chain depth 2 (slot -> xl). No max-subtraction (logits tiny; verified R11):
// z/acc are independent accumulations -> compiler can pipeline iterations.
__global__ __launch_bounds__(256) void k_attn(
    const ushort* __restrict__ xlb, const ushort* __restrict__ xrb,
    const int* __restrict__ slot_src, const float* __restrict__ slot_emb,
    const int* __restrict__ rowptr,
    const float* __restrict__ Wep, const float* __restrict__ attp,
    const float* __restrict__ cbp,
    const float* __restrict__ Woutp, const int* __restrict__ bid,
    float* __restrict__ outp,
    ushort* __restrict__ h_hi, ushort* __restrict__ h_lo,
    int N, int flags) {
  __shared__ float sv[4];
  __shared__ int   sb[4];
  int wid = threadIdx.x >> 6;
  int lane = threadIdx.x & 63;
  int n = blockIdx.x * 4 + wid;
  bool act = n < N;
  int nn = act ? n : (N - 1);
  int d0 = lane * 2;

  float we0[4], we1[4];
#pragma unroll
  for (int j = 0; j < 4; j++) {
    we0[j] = Wep[j * DD + d0];
    we1[j] = Wep[j * DD + d0 + 1];
  }
  int head = lane >> 4;
  float a0 = attp[head * 32 + (d0 & 31)];
  float a1 = attp[head * 32 + ((d0 + 1) & 31)];
  float xr0, xr1;
  {
    ushort2 u = *(const ushort2*)&xrb[(size_t)nn * DD + d0];
    xr0 = bf2f(u.x); xr1 = bf2f(u.y);
  }

  float z = 0.f, acc0 = 0.f, acc1 = 0.f;
  int r0 = rowptr[nn], r1 = rowptr[nn + 1];
  for (int p = r0; p < r1; p++) {
    int s = slot_src[p];
    float4 f = *(const float4*)&slot_emb[(size_t)p * 4];
    ushort2 u = *(const ushort2*)&xlb[(size_t)s * DD + d0];
    float xv0 = bf2f(u.x), xv1 = bf2f(u.y);
    float ee0 = f.x * we0[0] + f.y * we0[1] + f.z * we0[2] + f.w * we0[3];
    float ee1 = f.x * we1[0] + f.y * we1[1] + f.z * we1[2] + f.w * we1[3];
    float g0 = xv0 + xr0 + ee0; g0 = g0 > 0.f ? g0 : NEG * g0;
    float g1 = xv1 + xr1 + ee1; g1 = g1 > 0.f ? g1 : NEG * g1;
    float pv = g0 * a0 + g1 * a1;
    pv += __shfl_xor(pv, 1);
    pv += __shfl_xor(pv, 2);
    pv += __shfl_xor(pv, 4);
    pv += __shfl_xor(pv, 8);
    float wj = __expf(pv);               // no max-subtraction: logits O(1)
    z += wj;
    acc0 += wj * xv0;
    acc1 += wj * xv1;
  }
  float inv = 1.f / (z + 1e-16f);
  float o0 = acc0 * inv + cbp[d0];
  float o1 = acc1 * inv + cbp[d0 + 1];
  if (flags & 1) { o0 = fmaxf(o0, 0.f); o1 = fmaxf(o1, 0.f); }

  if (flags & 2) {
    // fused head with per-block LDS pre-reduction
    float v = o0 * Woutp[d0] + o1 * Woutp[d0 + 1];
    v += __shfl_xor(v, 1);
    v += __shfl_xor(v, 2);
    v += __shfl_xor(v, 4);
    v += __shfl_xor(v, 8);
    v += __shfl_xor(v, 16);
    v += __shfl_xor(v, 32);
    if (lane == 0) {
      sv[wid] = act ? v : 0.f;
      sb[wid] = act ? bid[n] : -1;
    }
    __syncthreads();
    if (threadIdx.x == 0) {
      int i = 0;
      while (i < 4) {
        int b = sb[i];
        if (b < 0) { i++; continue; }
        float s2 = sv[i];
        int j = i + 1;
        while (j < 4 && sb[j] == b) { s2 += sv[j]; j++; }
        atomicAdd(&outp[b], s2);
        i = j;
      }
    }
  } else if (act) {
    ushort h0 = f2bf(o0), h1 = f2bf(o1);
    *(ushort2*)&h_hi[(size_t)n * DD + d0] = make_ushort2(h0, h1);
    *(ushort2*)&h_lo[(size_t)n * DD + d0] =
        make_ushort2(f2bf(o0 - bf2f(h0)), f2bf(o1 - bf2f(h1)));
  }
}

// ---------------- out init: out[g] = bout ----------------------------------------
__global__ void k_head_init(float* __restrict__ out, const float* __restrict__ bout, int G) {
  int i = blockIdx.x * blockDim.x + threadIdx.x;
  if (i < G) out[i] = bout[0];
}

extern "C" void kernel_launch(void* const* d_in, const int* in_sizes, int n_in,
                              void* d_out, int out_size, void* d_ws, size_t ws_size,
                              hipStream_t stream) {
  const float* atom_tables = (const float*)d_in[0];
  const float* bond_table  = (const float*)d_in[1];
  const float* Wl   = (const float*)d_in[2];
  const float* bl   = (const float*)d_in[3];
  const float* Wr   = (const float*)d_in[4];
  const float* br   = (const float*)d_in[5];
  const float* We   = (const float*)d_in[6];
  const float* att  = (const float*)d_in[7];
  const float* cb   = (const float*)d_in[8];
  const float* Wout = (const float*)d_in[9];
  const float* bout = (const float*)d_in[10];
  const int* x      = (const int*)d_in[11];
  const int* ei     = (const int*)d_in[12];
  const int* eattr  = (const int*)d_in[13];
  const int* bid    = (const int*)d_in[14];

  int N = in_sizes[11] / 9;
  int E = in_sizes[13];
  int G = out_size;          // NTASK == 1
  int L = in_sizes[3] / DD;  // 4 layers

  char* p = (char*)d_ws;
  auto alloc = [&](size_t bytes) {
    char* r = p;
    p += (bytes + 255) & ~(size_t)255;
    return r;
  };
  ushort* h_hi     = (ushort*)alloc((size_t)(N + 64) * DD * 2);  // 51.2 MB
  ushort* h_lo     = (ushort*)alloc((size_t)(N + 64) * DD * 2);  // 51.2 MB
  ushort* xlb      = (ushort*)alloc((size_t)N * DD * 2);         // 51.2 MB
  ushort* xrb      = (ushort*)alloc((size_t)N * DD * 2);         // 51.2 MB
  float*  e_emb    = (float*)alloc((size_t)E * 4 * 4);           // 6.4 MB
  float*  sums     = (float*)alloc((size_t)N * 4 * 4);           // loop_attr
  int*    rowptr   = (int*)alloc((size_t)(N + 1) * 4);
  int*    eid      = (int*)alloc((size_t)(E + N) * 4);
  int*    slot_src = (int*)alloc((size_t)(E + N) * 4);           // 2.4 MB
  float*  slot_emb = (float*)alloc((size_t)(E + N) * 4 * 4);     // 9.6 MB
  float*  cnt      = (float*)alloc((size_t)N * 4);
  int*    deg      = (int*)alloc((size_t)N * 4);
  int*    cursor   = (int*)alloc((size_t)N * 4);
  int nblk = (N + 2047) / 2048;
  int*    bsums    = (int*)alloc((size_t)nblk * 4);
  ushort* Bhi      = (ushort*)alloc((size_t)L * 2 * 16384 * 2);
  ushort* Blo      = (ushort*)alloc((size_t)L * 2 * 16384 * 2);
  float*  out      = (float*)d_out;

  // Diagnostic guard: ws too small -> clean absmax failure, not a memory fault.
  if ((size_t)(p - (char*)d_ws) > ws_size) return;

  hipLaunchKernelGGL(k_atom_enc, dim3((N * DD + 255) / 256), dim3(256), 0, stream,
                     x, atom_tables, h_hi, h_lo, N);
  hipLaunchKernelGGL(k_init, dim3((N + 255) / 256), dim3(256), 0, stream,
                     deg, cnt, sums, N);
  hipLaunchKernelGGL(k_edge_count, dim3((E + 255) / 256), dim3(256), 0, stream,
                     ei, eattr, bond_table, e_emb, sums, cnt, deg, E);
  hipLaunchKernelGGL(k_scan_block, dim3(nblk), dim3(256), 0, stream, deg, bsums, N);
  hipLaunchKernelGGL(k_scan_top, dim3(1), dim3(64), 0, stream, bsums, rowptr, nblk, N);
  hipLaunchKernelGGL(k_scan_down, dim3(nblk), dim3(256), 0, stream,
                     deg, bsums, rowptr, cursor, N);
  hipLaunchKernelGGL(k_scatter, dim3((E + N + 255) / 256), dim3(256), 0, stream,
                     ei, cursor, eid, E, N);
  hipLaunchKernelGGL(k_loopattr, dim3((N * 4 + 255) / 256), dim3(256), 0, stream,
                     sums, cnt, N);
  hipLaunchKernelGGL(k_slotfill, dim3((E + N + 255) / 256), dim3(256), 0, stream,
                     eid, ei, e_emb, sums, slot_src, slot_emb, E, E + N);
  {
    int total = L * 2 * 4 * 8 * 64;
    hipLaunchKernelGGL(k_wpack, dim3((total + 255) / 256), dim3(256), 0, stream,
                       Wl, Wr, Bhi, Blo, L);
  }
  hipLaunchKernelGGL(k_head_init, dim3((G + 255) / 256), dim3(256), 0, stream,
                     out, bout, G);

  for (int l = 0; l < L; l++) {
    const ushort* bhiL = Bhi + (size_t)(l * 2 + 0) * 16384;
    const ushort* bhiR = Bhi + (size_t)(l * 2 + 1) * 16384;
    const ushort* bloL = Blo + (size_t)(l * 2 + 0) * 16384;
    const ushort* bloR = Blo + (size_t)(l * 2 + 1) * 16384;
    hipLaunchKernelGGL(k_gemm2_mfma, dim3((N + 63) / 64), dim3(256), 0, stream,
                       h_hi, h_lo, bhiL, bloL, bhiR, bloR,
                       bl + (size_t)l * DD, br + (size_t)l * DD, xlb, xrb, N);
    int flags = (l < L - 1) ? 1 : 2;   // relu inner; head-fusion last
    hipLaunchKernelGGL(k_attn, dim3((N + 3) / 4), dim3(256), 0, stream,
                       xlb, xrb, slot_src, slot_emb, rowptr,
                       We + (size_t)l * 4 * DD, att + (size_t)l * 4 * 32,
                       cb + (size_t)l * DD, Wout, bid, out, h_hi, h_lo, N, flags);
  }
}

// Round 16
// 1088.655 us; speedup vs baseline: 1.3470x; 1.1186x over previous
//
#include <hip/hip_runtime.h>
#include <hip/hip_bf16.h>

#define DD 128
#define NEG 0.2f

typedef short bf16x8 __attribute__((ext_vector_type(8)));
typedef float f32x4 __attribute__((ext_vector_type(4)));

__device__ inline ushort f2bf(float x) {
  unsigned u = __float_as_uint(x);
  return (ushort)((u + 0x7FFF + ((u >> 16) & 1)) >> 16);
}
__device__ inline float bf2f(ushort u) { return __uint_as_float((unsigned)u << 16); }

// h global layout is CHUNK-SWIZZLED for conflict-free LDS staging in the GEMM:
// element (n,d) lives at row n, position SW(n,d) = (((d>>3)^(n&7))<<3)|(d&7).
// Writers (atom_enc, attn epilogue) apply SW; the GEMM copies rows linearly into
// LDS via global_load_lds, so LDS inherits the swizzle and ds_read_b128 A-frags
// land on 8 distinct banks (2 lanes/bank = free, m136).
__device__ inline int swz_d(int n, int d) {
  return (((d >> 3) ^ (n & 7)) << 3) | (d & 7);
}

// ---------------- atom encoder: writes h as hi/lo bf16 split (swizzled) ----------
__global__ void k_atom_enc(const int* __restrict__ x, const float* __restrict__ tab,
                           ushort* __restrict__ h_hi, ushort* __restrict__ h_lo, int N) {
  int idx = blockIdx.x * blockDim.x + threadIdx.x;
  if (idx >= N * DD) return;
  int n = idx >> 7, d = idx & 127;
  const int* xr = x + n * 9;
  float s = 0.f;
#pragma unroll
  for (int f = 0; f < 9; f++) s += tab[(f * 16 + xr[f]) * DD + d];
  ushort hi = f2bf(s);
  size_t o = (size_t)n * DD + swz_d(n, d);
  h_hi[o] = hi;
  h_lo[o] = f2bf(s - bf2f(hi));
}

// ---------------- init deg(=1 self loop), cnt, sums ----------------
__global__ void k_init(int* __restrict__ deg, float* __restrict__ cnt,
                       float* __restrict__ sums, int N) {
  int i = blockIdx.x * blockDim.x + threadIdx.x;
  if (i >= N) return;
  deg[i] = 1;
  cnt[i] = 0.f;
  sums[i * 4 + 0] = 0.f; sums[i * 4 + 1] = 0.f;
  sums[i * 4 + 2] = 0.f; sums[i * 4 + 3] = 0.f;
}

// ---------------- per real edge: bond emb, per-dst sums/cnt/deg ----------------
__global__ void k_edge_count(const int* __restrict__ ei, const int* __restrict__ eattr,
                             const float* __restrict__ btab, float* __restrict__ e_emb,
                             float* __restrict__ sums, float* __restrict__ cnt,
                             int* __restrict__ deg, int E) {
  int e = blockIdx.x * blockDim.x + threadIdx.x;
  if (e >= E) return;
  int d = ei[E + e];
  int a = eattr[e];
  float f0 = btab[a * 4 + 0], f1 = btab[a * 4 + 1];
  float f2 = btab[a * 4 + 2], f3 = btab[a * 4 + 3];
  e_emb[e * 4 + 0] = f0; e_emb[e * 4 + 1] = f1;
  e_emb[e * 4 + 2] = f2; e_emb[e * 4 + 3] = f3;
  atomicAdd(&sums[d * 4 + 0], f0);
  atomicAdd(&sums[d * 4 + 1], f1);
  atomicAdd(&sums[d * 4 + 2], f2);
  atomicAdd(&sums[d * 4 + 3], f3);
  atomicAdd(&cnt[d], 1.0f);
  atomicAdd(&deg[d], 1);
}

// ---------------- loop_attr (in-place on sums) ----------------
__global__ void k_loopattr(float* __restrict__ sums, const float* __restrict__ cnt, int N) {
  int i = blockIdx.x * blockDim.x + threadIdx.x;
  if (i >= N * 4) return;
  sums[i] = sums[i] / fmaxf(cnt[i >> 2], 1.0f);
}

// ---------------- scan: chunk = 2048 (256 thr x 8 items) ----------------
__global__ void k_scan_block(const int* __restrict__ deg, int* __restrict__ bsums, int N) {
  __shared__ int sh[256];
  int t = threadIdx.x;
  int base = blockIdx.x * 2048 + t * 8;
  int tot = 0;
#pragma unroll
  for (int i = 0; i < 8; i++) tot += (base + i < N) ? deg[base + i] : 0;
  sh[t] = tot;
  __syncthreads();
  for (int off = 128; off > 0; off >>= 1) {
    if (t < off) sh[t] += sh[t + off];
    __syncthreads();
  }
  if (t == 0) bsums[blockIdx.x] = sh[0];
}

__global__ void k_scan_top(int* __restrict__ bsums, int* __restrict__ rowptr,
                           int nblk, int N) {
  if (threadIdx.x == 0 && blockIdx.x == 0) {
    int run = 0;
    for (int b = 0; b < nblk; b++) { int v = bsums[b]; bsums[b] = run; run += v; }
    rowptr[N] = run;
  }
}

__global__ void k_scan_down(const int* __restrict__ deg, const int* __restrict__ bsums,
                            int* __restrict__ rowptr, int* __restrict__ cursor, int N) {
  __shared__ int sh[256];
  int t = threadIdx.x;
  int base = blockIdx.x * 2048 + t * 8;
  int v[8]; int tot = 0;
#pragma unroll
  for (int i = 0; i < 8; i++) { v[i] = (base + i < N) ? deg[base + i] : 0; tot += v[i]; }
  sh[t] = tot;
  __syncthreads();
  for (int off = 1; off < 256; off <<= 1) {
    int xv = (t >= off) ? sh[t - off] : 0;
    __syncthreads();
    sh[t] += xv;
    __syncthreads();
  }
  int run = bsums[blockIdx.x] + sh[t] - tot;
#pragma unroll
  for (int i = 0; i < 8; i++) {
    if (base + i < N) { rowptr[base + i] = run; cursor[base + i] = run; run += v[i]; }
  }
}

// ---------------- scatter edge ids into CSR -------------------------------------
__global__ void k_scatter(const int* __restrict__ ei, int* __restrict__ cursor,
                          int* __restrict__ eid, int E, int N) {
  int t = blockIdx.x * blockDim.x + threadIdx.x;
  if (t >= E + N) return;
  int d = (t < E) ? ei[E + t] : (t - E);
  int pos = atomicAdd(&cursor[d], 1);
  eid[pos] = t;
}

// ---------------- slot packing: kill one pointer-chase level ---------------------
__global__ void k_slotfill(const int* __restrict__ eid, const int* __restrict__ ei,
                           const float* __restrict__ e_emb, const float* __restrict__ la,
                           int* __restrict__ slot_src, float* __restrict__ slot_emb,
                           int E, int total) {
  int p = blockIdx.x * blockDim.x + threadIdx.x;
  if (p >= total) return;
  int t = eid[p];
  bool re = t < E;
  int src = re ? ei[t] : (t - E);
  const float* fp = re ? &e_emb[(size_t)t * 4] : &la[(size_t)(t - E) * 4];
  slot_src[p] = src;
  *(float4*)&slot_emb[(size_t)p * 4] = *(const float4*)fp;
}

// ---------------- W prepack: bf16 hi/lo split into MFMA fragment order -----------
__global__ void k_wpack(const float* __restrict__ Wl, const float* __restrict__ Wr,
                        ushort* __restrict__ Bhi, ushort* __restrict__ Blo, int L) {
  int tid = blockIdx.x * blockDim.x + threadIdx.x;
  int total = L * 2 * 4 * 8 * 64;
  if (tid >= total) return;
  int lane = tid & 63;
  int nt = (tid >> 6) & 7;
  int kb = (tid >> 9) & 3;
  int mat = (tid >> 11) & 1;
  int layer = tid >> 12;
  const float* W = (mat ? Wr : Wl) + (size_t)layer * DD * DD;
  int kbase = kb * 32 + (lane >> 4) * 8;
  int n = nt * 16 + (lane & 15);
  size_t out = (size_t)(layer * 2 + mat) * 16384 +
               ((size_t)(kb * 8 + nt) * 64 + lane) * 8;
#pragma unroll
  for (int j = 0; j < 8; j++) {
    float xv = W[(size_t)(kbase + j) * DD + n];
    ushort h_ = f2bf(xv);
    float fh = __uint_as_float((unsigned)h_ << 16);
    ushort l_ = f2bf(xv - fh);
    Bhi[out + j] = h_;
    Blo[out + j] = l_;
  }
}

// ---------------- fused xl/xr GEMM: async LDS staging + bf16x3 MFMA --------------
// A tile (64 rows x 128 k, hi+lo = 32 KB) staged via global_load_lds width=16
// (linear copy; global layout pre-swizzled so LDS frags are conflict-free).
// B frags stream from prepacked global (L2-hot). Wave w: 4 M-tiles x 2 N-tiles
// x 2 mats, 192 MFMA.
__global__ __launch_bounds__(256) void k_gemm2_mfma(
    const ushort* __restrict__ h_hi, const ushort* __restrict__ h_lo,
    const ushort* __restrict__ bhiL, const ushort* __restrict__ bloL,
    const ushort* __restrict__ bhiR, const ushort* __restrict__ bloR,
    const float* __restrict__ bl, const float* __restrict__ br,
    ushort* __restrict__ xlb, ushort* __restrict__ xrb, int N) {
  __shared__ ushort sAhi[64 * 128];   // 16 KB, swizzled (inherited from global)
  __shared__ ushort sAlo[64 * 128];   // 16 KB
  int t = threadIdx.x;
  int lane = t & 63, w = t >> 6;
  int A0 = blockIdx.x * 64;

  // ---- async stage: each wave issues 4+4 gload_lds of 1 KB (lane*16B) ----
  {
    const char* ghi = (const char*)(h_hi + (size_t)A0 * DD);
    const char* glo = (const char*)(h_lo + (size_t)A0 * DD);
#pragma unroll
    for (int i = 0; i < 4; i++) {
      int off = (w * 4 + i) * 1024 + lane * 16;   // per-lane global byte offset
      int lbase = (w * 4 + i) * 1024;             // wave-uniform LDS base
      __builtin_amdgcn_global_load_lds(
          (const __attribute__((address_space(1))) void*)(ghi + off),
          (__attribute__((address_space(3))) void*)((char*)sAhi + lbase), 16, 0, 0);
      __builtin_amdgcn_global_load_lds(
          (const __attribute__((address_space(1))) void*)(glo + off),
          (__attribute__((address_space(3))) void*)((char*)sAlo + lbase), 16, 0, 0);
    }
  }
  __syncthreads();   // compiler emits vmcnt(0) drain before barrier

  int arow = lane & 15;
  int kg = lane >> 4;

  f32x4 accL[4][2], accR[4][2];
#pragma unroll
  for (int mt = 0; mt < 4; mt++)
#pragma unroll
    for (int nti = 0; nti < 2; nti++) {
      accL[mt][nti] = (f32x4){0.f, 0.f, 0.f, 0.f};
      accR[mt][nti] = (f32x4){0.f, 0.f, 0.f, 0.f};
    }

#pragma unroll
  for (int kb = 0; kb < 4; kb++) {
    bf16x8 ahi[4], alo[4];
    int c = kb * 4 + kg;                    // 16B chunk index within row
#pragma unroll
    for (int mt = 0; mt < 4; mt++) {
      int boff = (mt * 16 + arow) * 256 + ((c ^ (arow & 7)) << 4);
      ahi[mt] = *(const bf16x8*)((const char*)sAhi + boff);
      alo[mt] = *(const bf16x8*)((const char*)sAlo + boff);
    }
#pragma unroll
    for (int nti = 0; nti < 2; nti++) {
      int nt = w * 2 + nti;
      size_t fo = ((size_t)(kb * 8 + nt) * 64 + lane) * 8;
      bf16x8 bhl = *(const bf16x8*)(bhiL + fo);
      bf16x8 bll = *(const bf16x8*)(bloL + fo);
      bf16x8 bhr = *(const bf16x8*)(bhiR + fo);
      bf16x8 blr = *(const bf16x8*)(bloR + fo);
#pragma unroll
      for (int mt = 0; mt < 4; mt++) {
        accL[mt][nti] = __builtin_amdgcn_mfma_f32_16x16x32_bf16(ahi[mt], bhl, accL[mt][nti], 0, 0, 0);
        accR[mt][nti] = __builtin_amdgcn_mfma_f32_16x16x32_bf16(ahi[mt], bhr, accR[mt][nti], 0, 0, 0);
        accL[mt][nti] = __builtin_amdgcn_mfma_f32_16x16x32_bf16(ahi[mt], bll, accL[mt][nti], 0, 0, 0);
        accR[mt][nti] = __builtin_amdgcn_mfma_f32_16x16x32_bf16(ahi[mt], blr, accR[mt][nti], 0, 0, 0);
        accL[mt][nti] = __builtin_amdgcn_mfma_f32_16x16x32_bf16(alo[mt], bhl, accL[mt][nti], 0, 0, 0);
        accR[mt][nti] = __builtin_amdgcn_mfma_f32_16x16x32_bf16(alo[mt], bhr, accR[mt][nti], 0, 0, 0);
      }
    }
  }

  int col = lane & 15;
  int rgrp = (lane >> 4) * 4;
#pragma unroll
  for (int nti = 0; nti < 2; nti++) {
    int n = (w * 2 + nti) * 16 + col;
    float bLv = bl[n], bRv = br[n];
#pragma unroll
    for (int mt = 0; mt < 4; mt++) {
#pragma unroll
      for (int r = 0; r < 4; r++) {
        int atom = A0 + mt * 16 + rgrp + r;
        if (atom < N) {
          xlb[(size_t)atom * DD + n] = f2bf(accL[mt][nti][r] + bLv);
          xrb[(size_t)atom * DD + n] = f2bf(accR[mt][nti][r] + bRv);
        }
      }
    }
  }
}

// ---------------- attention: R12 structure (measured-best, 158 us) ---------------
__global__ __launch_bounds__(256) void k_attn(
    const ushort* __restrict__ xlb, const ushort* __restrict__ xrb,
    const int* __restrict__ slot_src, const float* __restrict__ slot_emb,
    const int* __restrict__ rowptr,
    const float* __restrict__ Wep, const float* __restrict__ attp,
    const float* __restrict__ cbp,
    const float* __restrict__ Woutp, const int* __restrict__ bid,
    float* __restrict__ outp,
    ushort* __restrict__ h_hi, ushort* __restrict__ h_lo,
    int N, int flags) {
  __shared__ float sv[4];
  __shared__ int   sb[4];
  int wid = threadIdx.x >> 6;
  int lane = threadIdx.x & 63;
  int n = blockIdx.x * 4 + wid;
  bool act = n < N;
  int nn = act ? n : (N - 1);
  int d0 = lane * 2;

  float we0[4], we1[4];
#pragma unroll
  for (int j = 0; j < 4; j++) {
    we0[j] = Wep[j * DD + d0];
    we1[j] = Wep[j * DD + d0 + 1];
  }
  int head = lane >> 4;
  float a0 = attp[head * 32 + (d0 & 31)];
  float a1 = attp[head * 32 + ((d0 + 1) & 31)];
  float xr0, xr1;
  {
    ushort2 u = *(const ushort2*)&xrb[(size_t)nn * DD + d0];
    xr0 = bf2f(u.x); xr1 = bf2f(u.y);
  }

  float z = 0.f, acc0 = 0.f, acc1 = 0.f;
  int r0 = rowptr[nn], r1 = rowptr[nn + 1];
  for (int p = r0; p < r1; p++) {
    int s = slot_src[p];
    float4 f = *(const float4*)&slot_emb[(size_t)p * 4];
    ushort2 u = *(const ushort2*)&xlb[(size_t)s * DD + d0];
    float xv0 = bf2f(u.x), xv1 = bf2f(u.y);
    float ee0 = f.x * we0[0] + f.y * we0[1] + f.z * we0[2] + f.w * we0[3];
    float ee1 = f.x * we1[0] + f.y * we1[1] + f.z * we1[2] + f.w * we1[3];
    float g0 = xv0 + xr0 + ee0; g0 = g0 > 0.f ? g0 : NEG * g0;
    float g1 = xv1 + xr1 + ee1; g1 = g1 > 0.f ? g1 : NEG * g1;
    float pv = g0 * a0 + g1 * a1;
    pv += __shfl_xor(pv, 1);
    pv += __shfl_xor(pv, 2);
    pv += __shfl_xor(pv, 4);
    pv += __shfl_xor(pv, 8);
    float wj = __expf(pv);               // no max-subtraction: logits O(1)
    z += wj;
    acc0 += wj * xv0;
    acc1 += wj * xv1;
  }
  float inv = 1.f / (z + 1e-16f);
  float o0 = acc0 * inv + cbp[d0];
  float o1 = acc1 * inv + cbp[d0 + 1];
  if (flags & 1) { o0 = fmaxf(o0, 0.f); o1 = fmaxf(o1, 0.f); }

  if (flags & 2) {
    float v = o0 * Woutp[d0] + o1 * Woutp[d0 + 1];
    v += __shfl_xor(v, 1);
    v += __shfl_xor(v, 2);
    v += __shfl_xor(v, 4);
    v += __shfl_xor(v, 8);
    v += __shfl_xor(v, 16);
    v += __shfl_xor(v, 32);
    if (lane == 0) {
      sv[wid] = act ? v : 0.f;
      sb[wid] = act ? bid[n] : -1;
    }
    __syncthreads();
    if (threadIdx.x == 0) {
      int i = 0;
      while (i < 4) {
        int b = sb[i];
        if (b < 0) { i++; continue; }
        float s2 = sv[i];
        int j = i + 1;
        while (j < 4 && sb[j] == b) { s2 += sv[j]; j++; }
        atomicAdd(&outp[b], s2);
        i = j;
      }
    }
  } else if (act) {
    // h write: swizzled layout (d0 even => d0,d0+1 share a 16B chunk)
    int dd = swz_d(n, d0);
    ushort h0 = f2bf(o0), h1 = f2bf(o1);
    *(ushort2*)&h_hi[(size_t)n * DD + dd] = make_ushort2(h0, h1);
    *(ushort2*)&h_lo[(size_t)n * DD + dd] =
        make_ushort2(f2bf(o0 - bf2f(h0)), f2bf(o1 - bf2f(h1)));
  }
}

// ---------------- out init: out[g] = bout ----------------------------------------
__global__ void k_head_init(float* __restrict__ out, const float* __restrict__ bout, int G) {
  int i = blockIdx.x * blockDim.x + threadIdx.x;
  if (i < G) out[i] = bout[0];
}

extern "C" void kernel_launch(void* const* d_in, const int* in_sizes, int n_in,
                              void* d_out, int out_size, void* d_ws, size_t ws_size,
                              hipStream_t stream) {
  const float* atom_tables = (const float*)d_in[0];
  const float* bond_table  = (const float*)d_in[1];
  const float* Wl   = (const float*)d_in[2];
  const float* bl   = (const float*)d_in[3];
  const float* Wr   = (const float*)d_in[4];
  const float* br   = (const float*)d_in[5];
  const float* We   = (const float*)d_in[6];
  const float* att  = (const float*)d_in[7];
  const float* cb   = (const float*)d_in[8];
  const float* Wout = (const float*)d_in[9];
  const float* bout = (const float*)d_in[10];
  const int* x      = (const int*)d_in[11];
  const int* ei     = (const int*)d_in[12];
  const int* eattr  = (const int*)d_in[13];
  const int* bid    = (const int*)d_in[14];

  int N = in_sizes[11] / 9;
  int E = in_sizes[13];
  int G = out_size;          // NTASK == 1
  int L = in_sizes[3] / DD;  // 4 layers

  char* p = (char*)d_ws;
  auto alloc = [&](size_t bytes) {
    char* r = p;
    p += (bytes + 255) & ~(size_t)255;
    return r;
  };
  ushort* h_hi     = (ushort*)alloc((size_t)(N + 64) * DD * 2);  // 51.2 MB
  ushort* h_lo     = (ushort*)alloc((size_t)(N + 64) * DD * 2);  // 51.2 MB
  ushort* xlb      = (ushort*)alloc((size_t)N * DD * 2);         // 51.2 MB
  ushort* xrb      = (ushort*)alloc((size_t)N * DD * 2);         // 51.2 MB
  float*  e_emb    = (float*)alloc((size_t)E * 4 * 4);           // 6.4 MB
  float*  sums     = (float*)alloc((size_t)N * 4 * 4);           // loop_attr
  int*    rowptr   = (int*)alloc((size_t)(N + 1) * 4);
  int*    eid      = (int*)alloc((size_t)(E + N) * 4);
  int*    slot_src = (int*)alloc((size_t)(E + N) * 4);
  float*  slot_emb = (float*)alloc((size_t)(E + N) * 4 * 4);
  float*  cnt      = (float*)alloc((size_t)N * 4);
  int*    deg      = (int*)alloc((size_t)N * 4);
  int*    cursor   = (int*)alloc((size_t)N * 4);
  int nblk = (N + 2047) / 2048;
  int*    bsums    = (int*)alloc((size_t)nblk * 4);
  ushort* Bhi      = (ushort*)alloc((size_t)L * 2 * 16384 * 2);
  ushort* Blo      = (ushort*)alloc((size_t)L * 2 * 16384 * 2);
  float*  out      = (float*)d_out;

  // Diagnostic guard: ws too small -> clean absmax failure, not a memory fault.
  if ((size_t)(p - (char*)d_ws) > ws_size) return;

  hipLaunchKernelGGL(k_atom_enc, dim3((N * DD + 255) / 256), dim3(256), 0, stream,
                     x, atom_tables, h_hi, h_lo, N);
  hipLaunchKernelGGL(k_init, dim3((N + 255) / 256), dim3(256), 0, stream,
                     deg, cnt, sums, N);
  hipLaunchKernelGGL(k_edge_count, dim3((E + 255) / 256), dim3(256), 0, stream,
                     ei, eattr, bond_table, e_emb, sums, cnt, deg, E);
  hipLaunchKernelGGL(k_scan_block, dim3(nblk), dim3(256), 0, stream, deg, bsums, N);
  hipLaunchKernelGGL(k_scan_top, dim3(1), dim3(64), 0, stream, bsums, rowptr, nblk, N);
  hipLaunchKernelGGL(k_scan_down, dim3(nblk), dim3(256), 0, stream,
                     deg, bsums, rowptr, cursor, N);
  hipLaunchKernelGGL(k_scatter, dim3((E + N + 255) / 256), dim3(256), 0, stream,
                     ei, cursor, eid, E, N);
  hipLaunchKernelGGL(k_loopattr, dim3((N * 4 + 255) / 256), dim3(256), 0, stream,
                     sums, cnt, N);
  hipLaunchKernelGGL(k_slotfill, dim3((E + N + 255) / 256), dim3(256), 0, stream,
                     eid, ei, e_emb, sums, slot_src, slot_emb, E, E + N);
  {
    int total = L * 2 * 4 * 8 * 64;
    hipLaunchKernelGGL(k_wpack, dim3((total + 255) / 256), dim3(256), 0, stream,
                       Wl, Wr, Bhi, Blo, L);
  }
  hipLaunchKernelGGL(k_head_init, dim3((G + 255) / 256), dim3(256), 0, stream,
                     out, bout, G);

  for (int l = 0; l < L; l++) {
    const ushort* bhiL = Bhi + (size_t)(l * 2 + 0) * 16384;
    const ushort* bhiR = Bhi + (size_t)(l * 2 + 1) * 16384;
    const ushort* bloL = Blo + (size_t)(l * 2 + 0) * 16384;
    const ushort* bloR = Blo + (size_t)(l * 2 + 1) * 16384;
    hipLaunchKernelGGL(k_gemm2_mfma, dim3((N + 63) / 64), dim3(256), 0, stream,
                       h_hi, h_lo, bhiL, bloL, bhiR, bloR,
                       bl + (size_t)l * DD, br + (size_t)l * DD, xlb, xrb, N);
    int flags = (l < L - 1) ? 1 : 2;   // relu inner; head-fusion last
    hipLaunchKernelGGL(k_attn, dim3((N + 3) / 4), dim3(256), 0, stream,
                       xlb, xrb, slot_src, slot_emb, rowptr,
                       We + (size_t)l * 4 * DD, att + (size_t)l * 4 * 32,
                       cb + (size_t)l * DD, Wout, bid, out, h_hi, h_lo, N, flags);
  }
}

// Round 17
// 1047.593 us; speedup vs baseline: 1.3998x; 1.0392x over previous
//
#include <hip/hip_runtime.h>
#include <hip/hip_bf16.h>

#define DD 128
#define NEG 0.2f

typedef short bf16x8 __attribute__((ext_vector_type(8)));
typedef float f32x4 __attribute__((ext_vector_type(4)));

__device__ inline ushort f2bf(float x) {
  unsigned u = __float_as_uint(x);
  return (ushort)((u + 0x7FFF + ((u >> 16) & 1)) >> 16);
}
__device__ inline float bf2f(ushort u) { return __uint_as_float((unsigned)u << 16); }

// h global layout is CHUNK-SWIZZLED for conflict-free LDS staging in the GEMM:
// element (n,d) lives at row n, position SW(n,d) = (((d>>3)^(n&7))<<3)|(d&7).
// Writers (atom_enc, attn epilogue) apply SW; the GEMM copies rows linearly into
// LDS via global_load_lds, so LDS inherits the swizzle and ds_read_b128 A-frags
// land on 8 distinct banks (2 lanes/bank = free, m136).
// A is PLAIN bf16 (no lo split): pipeline accuracy is already set by bf16 xl/xr
// storage; only W keeps the hi/lo split (costs nothing, L2-hot).
__device__ inline int swz_d(int n, int d) {
  return (((d >> 3) ^ (n & 7)) << 3) | (d & 7);
}

// ---------------- atom encoder: writes h as bf16 (swizzled) ----------------------
__global__ void k_atom_enc(const int* __restrict__ x, const float* __restrict__ tab,
                           ushort* __restrict__ h_hi, int N) {
  int idx = blockIdx.x * blockDim.x + threadIdx.x;
  if (idx >= N * DD) return;
  int n = idx >> 7, d = idx & 127;
  const int* xr = x + n * 9;
  float s = 0.f;
#pragma unroll
  for (int f = 0; f < 9; f++) s += tab[(f * 16 + xr[f]) * DD + d];
  h_hi[(size_t)n * DD + swz_d(n, d)] = f2bf(s);
}

// ---------------- init deg(=1 self loop), cnt, sums ----------------
__global__ void k_init(int* __restrict__ deg, float* __restrict__ cnt,
                       float* __restrict__ sums, int N) {
  int i = blockIdx.x * blockDim.x + threadIdx.x;
  if (i >= N) return;
  deg[i] = 1;
  cnt[i] = 0.f;
  sums[i * 4 + 0] = 0.f; sums[i * 4 + 1] = 0.f;
  sums[i * 4 + 2] = 0.f; sums[i * 4 + 3] = 0.f;
}

// ---------------- per real edge: bond emb, per-dst sums/cnt/deg ----------------
__global__ void k_edge_count(const int* __restrict__ ei, const int* __restrict__ eattr,
                             const float* __restrict__ btab, float* __restrict__ e_emb,
                             float* __restrict__ sums, float* __restrict__ cnt,
                             int* __restrict__ deg, int E) {
  int e = blockIdx.x * blockDim.x + threadIdx.x;
  if (e >= E) return;
  int d = ei[E + e];
  int a = eattr[e];
  float f0 = btab[a * 4 + 0], f1 = btab[a * 4 + 1];
  float f2 = btab[a * 4 + 2], f3 = btab[a * 4 + 3];
  e_emb[e * 4 + 0] = f0; e_emb[e * 4 + 1] = f1;
  e_emb[e * 4 + 2] = f2; e_emb[e * 4 + 3] = f3;
  atomicAdd(&sums[d * 4 + 0], f0);
  atomicAdd(&sums[d * 4 + 1], f1);
  atomicAdd(&sums[d * 4 + 2], f2);
  atomicAdd(&sums[d * 4 + 3], f3);
  atomicAdd(&cnt[d], 1.0f);
  atomicAdd(&deg[d], 1);
}

// ---------------- loop_attr (in-place on sums) ----------------
__global__ void k_loopattr(float* __restrict__ sums, const float* __restrict__ cnt, int N) {
  int i = blockIdx.x * blockDim.x + threadIdx.x;
  if (i >= N * 4) return;
  sums[i] = sums[i] / fmaxf(cnt[i >> 2], 1.0f);
}

// ---------------- scan: chunk = 2048 (256 thr x 8 items) ----------------
__global__ void k_scan_block(const int* __restrict__ deg, int* __restrict__ bsums, int N) {
  __shared__ int sh[256];
  int t = threadIdx.x;
  int base = blockIdx.x * 2048 + t * 8;
  int tot = 0;
#pragma unroll
  for (int i = 0; i < 8; i++) tot += (base + i < N) ? deg[base + i] : 0;
  sh[t] = tot;
  __syncthreads();
  for (int off = 128; off > 0; off >>= 1) {
    if (t < off) sh[t] += sh[t + off];
    __syncthreads();
  }
  if (t == 0) bsums[blockIdx.x] = sh[0];
}

__global__ void k_scan_top(int* __restrict__ bsums, int* __restrict__ rowptr,
                           int nblk, int N) {
  if (threadIdx.x == 0 && blockIdx.x == 0) {
    int run = 0;
    for (int b = 0; b < nblk; b++) { int v = bsums[b]; bsums[b] = run; run += v; }
    rowptr[N] = run;
  }
}

__global__ void k_scan_down(const int* __restrict__ deg, const int* __restrict__ bsums,
                            int* __restrict__ rowptr, int* __restrict__ cursor, int N) {
  __shared__ int sh[256];
  int t = threadIdx.x;
  int base = blockIdx.x * 2048 + t * 8;
  int v[8]; int tot = 0;
#pragma unroll
  for (int i = 0; i < 8; i++) { v[i] = (base + i < N) ? deg[base + i] : 0; tot += v[i]; }
  sh[t] = tot;
  __syncthreads();
  for (int off = 1; off < 256; off <<= 1) {
    int xv = (t >= off) ? sh[t - off] : 0;
    __syncthreads();
    sh[t] += xv;
    __syncthreads();
  }
  int run = bsums[blockIdx.x] + sh[t] - tot;
#pragma unroll
  for (int i = 0; i < 8; i++) {
    if (base + i < N) { rowptr[base + i] = run; cursor[base + i] = run; run += v[i]; }
  }
}

// ---------------- scatter edge ids into CSR -------------------------------------
__global__ void k_scatter(const int* __restrict__ ei, int* __restrict__ cursor,
                          int* __restrict__ eid, int E, int N) {
  int t = blockIdx.x * blockDim.x + threadIdx.x;
  if (t >= E + N) return;
  int d = (t < E) ? ei[E + t] : (t - E);
  int pos = atomicAdd(&cursor[d], 1);
  eid[pos] = t;
}

// ---------------- slot packing: kill one pointer-chase level ---------------------
__global__ void k_slotfill(const int* __restrict__ eid, const int* __restrict__ ei,
                           const float* __restrict__ e_emb, const float* __restrict__ la,
                           int* __restrict__ slot_src, float* __restrict__ slot_emb,
                           int E, int total) {
  int p = blockIdx.x * blockDim.x + threadIdx.x;
  if (p >= total) return;
  int t = eid[p];
  bool re = t < E;
  int src = re ? ei[t] : (t - E);
  const float* fp = re ? &e_emb[(size_t)t * 4] : &la[(size_t)(t - E) * 4];
  slot_src[p] = src;
  *(float4*)&slot_emb[(size_t)p * 4] = *(const float4*)fp;
}

// ---------------- W prepack: bf16 hi/lo split into MFMA fragment order -----------
__global__ void k_wpack(const float* __restrict__ Wl, const float* __restrict__ Wr,
                        ushort* __restrict__ Bhi, ushort* __restrict__ Blo, int L) {
  int tid = blockIdx.x * blockDim.x + threadIdx.x;
  int total = L * 2 * 4 * 8 * 64;
  if (tid >= total) return;
  int lane = tid & 63;
  int nt = (tid >> 6) & 7;
  int kb = (tid >> 9) & 3;
  int mat = (tid >> 11) & 1;
  int layer = tid >> 12;
  const float* W = (mat ? Wr : Wl) + (size_t)layer * DD * DD;
  int kbase = kb * 32 + (lane >> 4) * 8;
  int n = nt * 16 + (lane & 15);
  size_t out = (size_t)(layer * 2 + mat) * 16384 +
               ((size_t)(kb * 8 + nt) * 64 + lane) * 8;
#pragma unroll
  for (int j = 0; j < 8; j++) {
    float xv = W[(size_t)(kbase + j) * DD + n];
    ushort h_ = f2bf(xv);
    float fh = __uint_as_float((unsigned)h_ << 16);
    ushort l_ = f2bf(xv - fh);
    Bhi[out + j] = h_;
    Blo[out + j] = l_;
  }
}

// ---------------- fused xl/xr GEMM: async LDS staging + bf16x2 MFMA --------------
// A tile (64 rows x 128 k bf16 = 16 KB) staged via global_load_lds width=16.
// A plain bf16; W hi/lo => 4 MFMA per (mt,nti): 2 per mat. 128 MFMA/block.
// 16 KB LDS/block -> ~8 blocks/CU co-resident, stage drain well hidden.
__global__ __launch_bounds__(256) void k_gemm2_mfma(
    const ushort* __restrict__ h_hi,
    const ushort* __restrict__ bhiL, const ushort* __restrict__ bloL,
    const ushort* __restrict__ bhiR, const ushort* __restrict__ bloR,
    const float* __restrict__ bl, const float* __restrict__ br,
    ushort* __restrict__ xlb, ushort* __restrict__ xrb, int N) {
  __shared__ ushort sAhi[64 * 128];   // 16 KB, swizzled (inherited from global)
  int t = threadIdx.x;
  int lane = t & 63, w = t >> 6;
  int A0 = blockIdx.x * 64;

  // ---- async stage: each wave issues 4 gload_lds of 1 KB (lane*16B) ----
  {
    const char* ghi = (const char*)(h_hi + (size_t)A0 * DD);
#pragma unroll
    for (int i = 0; i < 4; i++) {
      int off = (w * 4 + i) * 1024 + lane * 16;   // per-lane global byte offset
      int lbase = (w * 4 + i) * 1024;             // wave-uniform LDS base
      __builtin_amdgcn_global_load_lds(
          (const __attribute__((address_space(1))) void*)(ghi + off),
          (__attribute__((address_space(3))) void*)((char*)sAhi + lbase), 16, 0, 0);
    }
  }
  __syncthreads();   // compiler emits vmcnt(0) drain before barrier

  int arow = lane & 15;
  int kg = lane >> 4;

  f32x4 accL[4][2], accR[4][2];
#pragma unroll
  for (int mt = 0; mt < 4; mt++)
#pragma unroll
    for (int nti = 0; nti < 2; nti++) {
      accL[mt][nti] = (f32x4){0.f, 0.f, 0.f, 0.f};
      accR[mt][nti] = (f32x4){0.f, 0.f, 0.f, 0.f};
    }

#pragma unroll
  for (int kb = 0; kb < 4; kb++) {
    bf16x8 ahi[4];
    int c = kb * 4 + kg;                    // 16B chunk index within row
#pragma unroll
    for (int mt = 0; mt < 4; mt++) {
      int boff = (mt * 16 + arow) * 256 + ((c ^ (arow & 7)) << 4);
      ahi[mt] = *(const bf16x8*)((const char*)sAhi + boff);
    }
#pragma unroll
    for (int nti = 0; nti < 2; nti++) {
      int nt = w * 2 + nti;
      size_t fo = ((size_t)(kb * 8 + nt) * 64 + lane) * 8;
      bf16x8 bhl = *(const bf16x8*)(bhiL + fo);
      bf16x8 bll = *(const bf16x8*)(bloL + fo);
      bf16x8 bhr = *(const bf16x8*)(bhiR + fo);
      bf16x8 blr = *(const bf16x8*)(bloR + fo);
#pragma unroll
      for (int mt = 0; mt < 4; mt++) {
        accL[mt][nti] = __builtin_amdgcn_mfma_f32_16x16x32_bf16(ahi[mt], bhl, accL[mt][nti], 0, 0, 0);
        accR[mt][nti] = __builtin_amdgcn_mfma_f32_16x16x32_bf16(ahi[mt], bhr, accR[mt][nti], 0, 0, 0);
        accL[mt][nti] = __builtin_amdgcn_mfma_f32_16x16x32_bf16(ahi[mt], bll, accL[mt][nti], 0, 0, 0);
        accR[mt][nti] = __builtin_amdgcn_mfma_f32_16x16x32_bf16(ahi[mt], blr, accR[mt][nti], 0, 0, 0);
      }
    }
  }

  int col = lane & 15;
  int rgrp = (lane >> 4) * 4;
#pragma unroll
  for (int nti = 0; nti < 2; nti++) {
    int n = (w * 2 + nti) * 16 + col;
    float bLv = bl[n], bRv = br[n];
#pragma unroll
    for (int mt = 0; mt < 4; mt++) {
#pragma unroll
      for (int r = 0; r < 4; r++) {
        int atom = A0 + mt * 16 + rgrp + r;
        if (atom < N) {
          xlb[(size_t)atom * DD + n] = f2bf(accL[mt][nti][r] + bLv);
          xrb[(size_t)atom * DD + n] = f2bf(accR[mt][nti][r] + bRv);
        }
      }
    }
  }
}

// ---------------- attention: R12 structure (measured-best, 158 us) ---------------
__global__ __launch_bounds__(256) void k_attn(
    const ushort* __restrict__ xlb, const ushort* __restrict__ xrb,
    const int* __restrict__ slot_src, const float* __restrict__ slot_emb,
    const int* __restrict__ rowptr,
    const float* __restrict__ Wep, const float* __restrict__ attp,
    const float* __restrict__ cbp,
    const float* __restrict__ Woutp, const int* __restrict__ bid,
    float* __restrict__ outp,
    ushort* __restrict__ h_hi,
    int N, int flags) {
  __shared__ float sv[4];
  __shared__ int   sb[4];
  int wid = threadIdx.x >> 6;
  int lane = threadIdx.x & 63;
  int n = blockIdx.x * 4 + wid;
  bool act = n < N;
  int nn = act ? n : (N - 1);
  int d0 = lane * 2;

  float we0[4], we1[4];
#pragma unroll
  for (int j = 0; j < 4; j++) {
    we0[j] = Wep[j * DD + d0];
    we1[j] = Wep[j * DD + d0 + 1];
  }
  int head = lane >> 4;
  float a0 = attp[head * 32 + (d0 & 31)];
  float a1 = attp[head * 32 + ((d0 + 1) & 31)];
  float xr0, xr1;
  {
    ushort2 u = *(const ushort2*)&xrb[(size_t)nn * DD + d0];
    xr0 = bf2f(u.x); xr1 = bf2f(u.y);
  }

  float z = 0.f, acc0 = 0.f, acc1 = 0.f;
  int r0 = rowptr[nn], r1 = rowptr[nn + 1];
  for (int p = r0; p < r1; p++) {
    int s = slot_src[p];
    float4 f = *(const float4*)&slot_emb[(size_t)p * 4];
    ushort2 u = *(const ushort2*)&xlb[(size_t)s * DD + d0];
    float xv0 = bf2f(u.x), xv1 = bf2f(u.y);
    float ee0 = f.x * we0[0] + f.y * we0[1] + f.z * we0[2] + f.w * we0[3];
    float ee1 = f.x * we1[0] + f.y * we1[1] + f.z * we1[2] + f.w * we1[3];
    float g0 = xv0 + xr0 + ee0; g0 = g0 > 0.f ? g0 : NEG * g0;
    float g1 = xv1 + xr1 + ee1; g1 = g1 > 0.f ? g1 : NEG * g1;
    float pv = g0 * a0 + g1 * a1;
    pv += __shfl_xor(pv, 1);
    pv += __shfl_xor(pv, 2);
    pv += __shfl_xor(pv, 4);
    pv += __shfl_xor(pv, 8);
    float wj = __expf(pv);               // no max-subtraction: logits O(1)
    z += wj;
    acc0 += wj * xv0;
    acc1 += wj * xv1;
  }
  float inv = 1.f / (z + 1e-16f);
  float o0 = acc0 * inv + cbp[d0];
  float o1 = acc1 * inv + cbp[d0 + 1];
  if (flags & 1) { o0 = fmaxf(o0, 0.f); o1 = fmaxf(o1, 0.f); }

  if (flags & 2) {
    float v = o0 * Woutp[d0] + o1 * Woutp[d0 + 1];
    v += __shfl_xor(v, 1);
    v += __shfl_xor(v, 2);
    v += __shfl_xor(v, 4);
    v += __shfl_xor(v, 8);
    v += __shfl_xor(v, 16);
    v += __shfl_xor(v, 32);
    if (lane == 0) {
      sv[wid] = act ? v : 0.f;
      sb[wid] = act ? bid[n] : -1;
    }
    __syncthreads();
    if (threadIdx.x == 0) {
      int i = 0;
      while (i < 4) {
        int b = sb[i];
        if (b < 0) { i++; continue; }
        float s2 = sv[i];
        int j = i + 1;
        while (j < 4 && sb[j] == b) { s2 += sv[j]; j++; }
        atomicAdd(&outp[b], s2);
        i = j;
      }
    }
  } else if (act) {
    // h write: swizzled layout (d0 even => d0,d0+1 share a 16B chunk)
    int dd = swz_d(n, d0);
    *(ushort2*)&h_hi[(size_t)n * DD + dd] = make_ushort2(f2bf(o0), f2bf(o1));
  }
}

// ---------------- out init: out[g] = bout ----------------------------------------
__global__ void k_head_init(float* __restrict__ out, const float* __restrict__ bout, int G) {
  int i = blockIdx.x * blockDim.x + threadIdx.x;
  if (i < G) out[i] = bout[0];
}

extern "C" void kernel_launch(void* const* d_in, const int* in_sizes, int n_in,
                              void* d_out, int out_size, void* d_ws, size_t ws_size,
                              hipStream_t stream) {
  const float* atom_tables = (const float*)d_in[0];
  const float* bond_table  = (const float*)d_in[1];
  const float* Wl   = (const float*)d_in[2];
  const float* bl   = (const float*)d_in[3];
  const float* Wr   = (const float*)d_in[4];
  const float* br   = (const float*)d_in[5];
  const float* We   = (const float*)d_in[6];
  const float* att  = (const float*)d_in[7];
  const float* cb   = (const float*)d_in[8];
  const float* Wout = (const float*)d_in[9];
  const float* bout = (const float*)d_in[10];
  const int* x      = (const int*)d_in[11];
  const int* ei     = (const int*)d_in[12];
  const int* eattr  = (const int*)d_in[13];
  const int* bid    = (const int*)d_in[14];

  int N = in_sizes[11] / 9;
  int E = in_sizes[13];
  int G = out_size;          // NTASK == 1
  int L = in_sizes[3] / DD;  // 4 layers

  char* p = (char*)d_ws;
  auto alloc = [&](size_t bytes) {
    char* r = p;
    p += (bytes + 255) & ~(size_t)255;
    return r;
  };
  ushort* h_hi     = (ushort*)alloc((size_t)(N + 64) * DD * 2);  // 51.2 MB
  ushort* xlb      = (ushort*)alloc((size_t)N * DD * 2);         // 51.2 MB
  ushort* xrb      = (ushort*)alloc((size_t)N * DD * 2);         // 51.2 MB
  float*  e_emb    = (float*)alloc((size_t)E * 4 * 4);           // 6.4 MB
  float*  sums     = (float*)alloc((size_t)N * 4 * 4);           // loop_attr
  int*    rowptr   = (int*)alloc((size_t)(N + 1) * 4);
  int*    eid      = (int*)alloc((size_t)(E + N) * 4);
  int*    slot_src = (int*)alloc((size_t)(E + N) * 4);
  float*  slot_emb = (float*)alloc((size_t)(E + N) * 4 * 4);
  float*  cnt      = (float*)alloc((size_t)N * 4);
  int*    deg      = (int*)alloc((size_t)N * 4);
  int*    cursor   = (int*)alloc((size_t)N * 4);
  int nblk = (N + 2047) / 2048;
  int*    bsums    = (int*)alloc((size_t)nblk * 4);
  ushort* Bhi      = (ushort*)alloc((size_t)L * 2 * 16384 * 2);
  ushort* Blo      = (ushort*)alloc((size_t)L * 2 * 16384 * 2);
  float*  out      = (float*)d_out;

  // Diagnostic guard: ws too small -> clean absmax failure, not a memory fault.
  if ((size_t)(p - (char*)d_ws) > ws_size) return;

  hipLaunchKernelGGL(k_atom_enc, dim3((N * DD + 255) / 256), dim3(256), 0, stream,
                     x, atom_tables, h_hi, N);
  hipLaunchKernelGGL(k_init, dim3((N + 255) / 256), dim3(256), 0, stream,
                     deg, cnt, sums, N);
  hipLaunchKernelGGL(k_edge_count, dim3((E + 255) / 256), dim3(256), 0, stream,
                     ei, eattr, bond_table, e_emb, sums, cnt, deg, E);
  hipLaunchKernelGGL(k_scan_block, dim3(nblk), dim3(256), 0, stream, deg, bsums, N);
  hipLaunchKernelGGL(k_scan_top, dim3(1), dim3(64), 0, stream, bsums, rowptr, nblk, N);
  hipLaunchKernelGGL(k_scan_down, dim3(nblk), dim3(256), 0, stream,
                     deg, bsums, rowptr, cursor, N);
  hipLaunchKernelGGL(k_scatter, dim3((E + N + 255) / 256), dim3(256), 0, stream,
                     ei, cursor, eid, E, N);
  hipLaunchKernelGGL(k_loopattr, dim3((N * 4 + 255) / 256), dim3(256), 0, stream,
                     sums, cnt, N);
  hipLaunchKernelGGL(k_slotfill, dim3((E + N + 255) / 256), dim3(256), 0, stream,
                     eid, ei, e_emb, sums, slot_src, slot_emb, E, E + N);
  {
    int total = L * 2 * 4 * 8 * 64;
    hipLaunchKernelGGL(k_wpack, dim3((total + 255) / 256), dim3(256), 0, stream,
                       Wl, Wr, Bhi, Blo, L);
  }
  hipLaunchKernelGGL(k_head_init, dim3((G + 255) / 256), dim3(256), 0, stream,
                     out, bout, G);

  for (int l = 0; l < L; l++) {
    const ushort* bhiL = Bhi + (size_t)(l * 2 + 0) * 16384;
    const ushort* bhiR = Bhi + (size_t)(l * 2 + 1) * 16384;
    const ushort* bloL = Blo + (size_t)(l * 2 + 0) * 16384;
    const ushort* bloR = Blo + (size_t)(l * 2 + 1) * 16384;
    hipLaunchKernelGGL(k_gemm2_mfma, dim3((N + 63) / 64), dim3(256), 0, stream,
                       h_hi, bhiL, bloL, bhiR, bloR,
                       bl + (size_t)l * DD, br + (size_t)l * DD, xlb, xrb, N);
    int flags = (l < L - 1) ? 1 : 2;   // relu inner; head-fusion last
    hipLaunchKernelGGL(k_attn, dim3((N + 3) / 4), dim3(256), 0, stream,
                       xlb, xrb, slot_src, slot_emb, rowptr,
                       We + (size_t)l * 4 * DD, att + (size_t)l * 4 * 32,
                       cb + (size_t)l * DD, Wout, bid, out, h_hi, N, flags);
  }
}